// Round 7
// baseline (875.285 us; speedup 1.0000x reference)
//
#include <hip/hip_runtime.h>
#include <stdint.h>

#define T_STEPS 128
#define BATCH   64
#define EMBED   256
#define HIDDEN  512
#define VOCAB   10000
#define M_ROWS  (T_STEPS*BATCH)   // 8192
#define NGATE   (4*HIDDEN)        // 2048
#define NBLK    32                // lstm worker blocks

typedef __attribute__((ext_vector_type(2))) float  f32x2;
typedef __attribute__((ext_vector_type(4))) float  f32x4;
typedef __attribute__((ext_vector_type(4))) int    i32x4;
typedef __attribute__((ext_vector_type(8))) __bf16 bf16x8;

static __device__ __forceinline__ unsigned short f32_to_bf16(float f) {
    union { float f; uint32_t u; } v; v.f = f;
    uint32_t u = v.u;
    return (unsigned short)((u + 0x7FFFu + ((u >> 16) & 1u)) >> 16);  // RNE
}
static __device__ __forceinline__ float sigf(float x) {
    return 1.f / (1.f + __expf(-x));
}
static __device__ __forceinline__ float tanhfast(float x) {
    float e = __expf(2.f * fminf(fmaxf(x, -15.f), 15.f));
    return (e - 1.f) / (e + 1.f);
}

// IC-coherent (bypass L1+L2) primitives — the ONLY verified cross-XCD path.
static __device__ __forceinline__ i32x4 ld16ic(const void* p) {
    i32x4 r; asm volatile("global_load_dwordx4 %0, %1, off sc0 sc1" : "=v"(r) : "v"(p)); return r;
}
static __device__ __forceinline__ void st4ic(void* p, unsigned v) {
    asm volatile("global_store_dword %0, %1, off sc0 sc1" :: "v"(p), "v"(v) : "memory");
}

// ---------------------------------------------------------------------------
// W [512][10000] f32  ->  Wt [10000][512] bf16   (tiled transpose + convert)
// ---------------------------------------------------------------------------
__global__ void wt_convert(const float* __restrict__ W, unsigned short* __restrict__ Wt) {
    __shared__ float tile[32][33];
    int n0 = blockIdx.x * 32;
    int k0 = blockIdx.y * 32;
    int tx = threadIdx.x, ty = threadIdx.y;
    int n = n0 + tx;
    if (n < VOCAB) tile[ty][tx] = W[(size_t)(k0 + ty) * VOCAB + n];
    __syncthreads();
    int nn = n0 + ty;
    if (nn < VOCAB) Wt[(size_t)nn * HIDDEN + k0 + tx] = f32_to_bf16(tile[tx][ty]);
}

// ---------------------------------------------------------------------------
// Wh_g [512 k][512 n] f32 -> WhT [4][512 n][512 k] bf16
// ---------------------------------------------------------------------------
__global__ void wh_convert(const float* __restrict__ Whi, const float* __restrict__ Whf,
                           const float* __restrict__ Whc, const float* __restrict__ Who,
                           unsigned short* __restrict__ WhT) {
    __shared__ float tile[32][33];
    int g = blockIdx.z;
    const float* Wg = (g == 0) ? Whi : (g == 1) ? Whf : (g == 2) ? Whc : Who;
    int n0 = blockIdx.x * 32, k0 = blockIdx.y * 32;
    int tx = threadIdx.x, ty = threadIdx.y;
    tile[ty][tx] = Wg[(size_t)(k0 + ty) * HIDDEN + n0 + tx];
    __syncthreads();
    WhT[((size_t)g * HIDDEN + n0 + ty) * HIDDEN + k0 + tx] = f32_to_bf16(tile[tx][ty]);
}

// ---------------------------------------------------------------------------
// xg[m][g*512+hc] = embeddings[input_[m]] @ W_xg + b_g   (fp32 tiled GEMM)
// ---------------------------------------------------------------------------
__global__ __launch_bounds__(256) void xproj(
    const int* __restrict__ idx, const float* __restrict__ Emb,
    const float* __restrict__ Wxi, const float* __restrict__ Wxf,
    const float* __restrict__ Wxc, const float* __restrict__ Wxo,
    const float* __restrict__ bi,  const float* __restrict__ bf_,
    const float* __restrict__ bc,  const float* __restrict__ bo,
    float* __restrict__ xg)
{
    __shared__ float At[32][132];   // [k][m], padded
    __shared__ float Bt[32][68];    // [k][n], padded
    int cb = blockIdx.x;            // 0..31 (8 col-blocks per gate)
    int rb = blockIdx.y;            // 0..63
    int g  = cb >> 3;
    int hc0 = (cb & 7) * 64;
    const float* Wg = (g == 0) ? Wxi : (g == 1) ? Wxf : (g == 2) ? Wxc : Wxo;
    const float* bg = (g == 0) ? bi  : (g == 1) ? bf_ : (g == 2) ? bc  : bo;
    int m0 = rb * 128;
    int tid = threadIdx.x;
    int tr = tid >> 4, tc = tid & 15;
    float acc[8][4] = {};

    for (int kc = 0; kc < EMBED; kc += 32) {
        #pragma unroll
        for (int i = 0; i < 4; ++i) {
            int s = tid + i * 256;            // 0..1023
            int row = s >> 3, k4 = s & 7;
            int er = idx[m0 + row];
            f32x4 v = *reinterpret_cast<const f32x4*>(Emb + (size_t)er * EMBED + kc + k4 * 4);
            #pragma unroll
            for (int j = 0; j < 4; ++j) At[k4 * 4 + j][row] = v[j];
        }
        #pragma unroll
        for (int i = 0; i < 2; ++i) {
            int s = tid + i * 256;            // 0..511
            int k = s >> 4, c4 = s & 15;
            f32x4 v = *reinterpret_cast<const f32x4*>(Wg + (size_t)(kc + k) * HIDDEN + hc0 + c4 * 4);
            *reinterpret_cast<f32x4*>(&Bt[k][c4 * 4]) = v;
        }
        __syncthreads();
        #pragma unroll 8
        for (int k = 0; k < 32; ++k) {
            f32x4 a0 = *reinterpret_cast<const f32x4*>(&At[k][tr * 8]);
            f32x4 a1 = *reinterpret_cast<const f32x4*>(&At[k][tr * 8 + 4]);
            f32x4 b4 = *reinterpret_cast<const f32x4*>(&Bt[k][tc * 4]);
            float av[8] = {a0[0],a0[1],a0[2],a0[3],a1[0],a1[1],a1[2],a1[3]};
            #pragma unroll
            for (int i = 0; i < 8; ++i)
                #pragma unroll
                for (int j = 0; j < 4; ++j)
                    acc[i][j] += av[i] * b4[j];
        }
        __syncthreads();
    }
    f32x4 bb = *reinterpret_cast<const f32x4*>(bg + hc0 + tc * 4);
    #pragma unroll
    for (int i = 0; i < 8; ++i) {
        int row = m0 + tr * 8 + i;
        f32x4 o;
        #pragma unroll
        for (int j = 0; j < 4; ++j) o[j] = acc[i][j] + bb[j];
        *reinterpret_cast<f32x4*>(xg + (size_t)row * NGATE + g * HIDDEN + hc0 + tc * 4) = o;
    }
}

// ---------------------------------------------------------------------------
// Persistent LSTM scan, 32 blocks x 512 threads, data-flow sync with
// per-block READY FLAGS (128B poll instead of 64KB re-read):
//   producer: h sc-stores -> vmcnt(0) -> __syncthreads -> tid0 sets
//             flags[t][bx] (IC store; h already ACKed at IC, so any reader
//             that sees the flag sees the data).
//   consumer: wave 0 polls the 32 flags of step t-1, barrier, then ONE
//             64KB IC data pass (no sentinel check needed).
// ---------------------------------------------------------------------------
__global__ __launch_bounds__(512) void lstm_scan(
    const float* __restrict__ xg,
    const unsigned short* __restrict__ WhT,   // [4][512][512] bf16
    unsigned short* hsbf,                     // [128][64][512] bf16
    float* __restrict__ hfin, float* __restrict__ cfin,
    unsigned* flags)                          // [128][32] dwords, pre-zeroed
{
    __shared__ __align__(16) unsigned char hstage[65536];  // 64 x 512 bf16, swizzled
    __shared__ float P_lds[4][64][17];                     // padded (bank)
    const int tid  = threadIdx.x;
    const int bx   = blockIdx.x;        // 0..31
    const int hc0  = bx * 16;
    const int lane = tid & 63, w = tid >> 6;
    const int wm   = w >> 2, wg = w & 3;

    // ---- preload Wh slice: wave (.,wg) lane l: col hc0+(l&15), 8 k per kstep
    bf16x8 breg[16];
    {
        const unsigned short* base =
            WhT + ((size_t)wg * HIDDEN + hc0 + (lane & 15)) * HIDDEN + (lane >> 4) * 8;
        #pragma unroll
        for (int ks = 0; ks < 16; ++ks)
            breg[ks] = *reinterpret_cast<const bf16x8*>(base + ks * 32);
    }

    // ---- update-thread mapping: thread -> (batch, hc pair)
    const int ub  = tid >> 3;          // 0..63
    const int uhp = tid & 7;           // 0..7
    const int uhc = hc0 + uhp * 2;
    float c0 = 0.f, c1 = 0.f;
    f32x2 xv[4];
    {
        const float* xrow = xg + (size_t)ub * NGATE + uhc;
        #pragma unroll
        for (int g = 0; g < 4; ++g)
            xv[g] = *reinterpret_cast<const f32x2*>(xrow + g * HIDDEN);
    }

    for (int t = 0; t < T_STEPS; ++t) {
        f32x4 acc0 = {0.f,0.f,0.f,0.f}, acc1 = {0.f,0.f,0.f,0.f};
        if (t > 0) {
            // ---- wave 0 polls the 32 ready-flags of step t-1 (lanes mirror)
            if (w == 0) {
                const unsigned* fl = flags + (size_t)(t - 1) * NBLK + (lane & 31);
                for (int rnd = 0; rnd < (1 << 16); ++rnd) {
                    unsigned v;
                    asm volatile("global_load_dword %0, %1, off sc0 sc1"
                                 : "=v"(v) : "v"(fl));
                    asm volatile("s_waitcnt vmcnt(0)" : "+v"(v));
                    if (__all(v != 0u)) break;
                    __builtin_amdgcn_s_sleep(1);
                }
            }
            __syncthreads();                       // flags observed by all
            // ---- ONE data pass: 8x16B per thread from IC
            const char* hb = (const char*)hsbf + (size_t)(t - 1) * 65536;
            i32x4 r0 = ld16ic(hb + (size_t)(0 * 512 + tid) * 16);
            i32x4 r1 = ld16ic(hb + (size_t)(1 * 512 + tid) * 16);
            i32x4 r2 = ld16ic(hb + (size_t)(2 * 512 + tid) * 16);
            i32x4 r3 = ld16ic(hb + (size_t)(3 * 512 + tid) * 16);
            i32x4 r4 = ld16ic(hb + (size_t)(4 * 512 + tid) * 16);
            i32x4 r5 = ld16ic(hb + (size_t)(5 * 512 + tid) * 16);
            i32x4 r6 = ld16ic(hb + (size_t)(6 * 512 + tid) * 16);
            i32x4 r7 = ld16ic(hb + (size_t)(7 * 512 + tid) * 16);
            asm volatile("s_waitcnt vmcnt(0)" ::: "memory");
            __builtin_amdgcn_sched_barrier(0);
#define STLDS(R, I) { int s16 = (I) * 512 + tid; int row = s16 >> 6, sl = s16 & 63; \
        *reinterpret_cast<i32x4*>(hstage + row * 1024 + ((sl ^ (row & 7)) << 4)) = R; }
            STLDS(r0, 0) STLDS(r1, 1) STLDS(r2, 2) STLDS(r3, 3)
            STLDS(r4, 4) STLDS(r5, 5) STLDS(r6, 6) STLDS(r7, 7)
#undef STLDS
            __syncthreads();                       // SYNC_A
            const int r0r = wm * 32 + (lane & 15);
            const int r1r = r0r + 16;
            #pragma unroll
            for (int ks = 0; ks < 16; ++ks) {
                int sl = ks * 4 + (lane >> 4);
                bf16x8 a0 = *reinterpret_cast<const bf16x8*>(
                    hstage + r0r * 1024 + ((sl ^ (r0r & 7)) << 4));
                bf16x8 a1 = *reinterpret_cast<const bf16x8*>(
                    hstage + r1r * 1024 + ((sl ^ (r1r & 7)) << 4));
                acc0 = __builtin_amdgcn_mfma_f32_16x16x32_bf16(a0, breg[ks], acc0, 0, 0, 0);
                acc1 = __builtin_amdgcn_mfma_f32_16x16x32_bf16(a1, breg[ks], acc1, 0, 0, 0);
            }
        }
        // ---- exchange preacts via LDS (C layout: col=lane&15, row=(lane>>4)*4+r)
        {
            int colr = lane & 15, rowb = (lane >> 4) * 4;
            #pragma unroll
            for (int r = 0; r < 4; ++r) {
                P_lds[wg][wm * 32 + rowb + r][colr]      = acc0[r];
                P_lds[wg][wm * 32 + 16 + rowb + r][colr] = acc1[r];
            }
        }
        __syncthreads();                           // SYNC_B
        // ---- cell update: 2 (b,hc) per thread
        {
            int hp2 = uhp * 2;
            float pi0 = P_lds[0][ub][hp2] + xv[0][0], pi1 = P_lds[0][ub][hp2+1] + xv[0][1];
            float pf0 = P_lds[1][ub][hp2] + xv[1][0], pf1 = P_lds[1][ub][hp2+1] + xv[1][1];
            float pg0 = P_lds[2][ub][hp2] + xv[2][0], pg1 = P_lds[2][ub][hp2+1] + xv[2][1];
            float po0 = P_lds[3][ub][hp2] + xv[3][0], po1 = P_lds[3][ub][hp2+1] + xv[3][1];
            float i0 = sigf(pi0), i1 = sigf(pi1);
            float f0 = sigf(pf0), f1 = sigf(pf1);
            float g0 = tanhfast(pg0), g1 = tanhfast(pg1);
            float o0 = sigf(po0), o1 = sigf(po1);
            c0 = f0 * c0 + i0 * g0;
            c1 = f1 * c1 + i1 * g1;
            float h0 = o0 * tanhfast(c0);
            float h1 = o1 * tanhfast(c1);
            unsigned hp = ((unsigned)f32_to_bf16(h1) << 16) | (unsigned)f32_to_bf16(h0);
            // h publication store (IC)
            st4ic(reinterpret_cast<unsigned*>(hsbf)
                  + (size_t)(t * BATCH + ub) * 256 + (uhc >> 1), hp);
            if (t == T_STEPS - 1) {
                f32x2 hv = { h0, h1 };
                *reinterpret_cast<f32x2*>(hfin + (size_t)ub * HIDDEN + uhc) = hv;
            }
        }
        // ---- publication: drain h stores, then tid0 raises this block's flag
        asm volatile("s_waitcnt vmcnt(0)" ::: "memory");   // h stores ACKed at IC
        __syncthreads();                                   // ...by ALL threads
        if (t < T_STEPS - 1) {
            if (tid == 0)
                st4ic(flags + (size_t)t * NBLK + bx, 1u);
            // prefetch next step's x-gate row (after publication; overlaps poll)
            const float* xrow = xg + (size_t)((t + 1) * BATCH + ub) * NGATE + uhc;
            #pragma unroll
            for (int g = 0; g < 4; ++g)
                xv[g] = *reinterpret_cast<const f32x2*>(xrow + g * HIDDEN);
        }
    }
    // ---- final c
    {
        f32x2 cv = { c0, c1 };
        *reinterpret_cast<f32x2*>(cfin + (size_t)ub * HIDDEN + uhc) = cv;
    }
}

// ---------------------------------------------------------------------------
// out = hs_bf16 [8192,512] @ W_bf16^T [10000,512] + b   (bf16 MFMA, f32 acc)
// ---------------------------------------------------------------------------
__global__ __launch_bounds__(256) void out_proj(
    const unsigned short* __restrict__ Abf,   // [8192][512]
    const unsigned short* __restrict__ Btbf,  // [10000][512]
    const float* __restrict__ bias,           // [10000]
    float* __restrict__ Cout)                 // [8192][10000] f32
{
    __shared__ __align__(16) char sA[128 * 128];  // 128 rows x 64 bf16
    __shared__ __align__(16) char sB[80 * 128];   // 80 rows x 64 bf16
    int n0 = blockIdx.x * 80;
    int m0 = blockIdx.y * 128;
    int tid = threadIdx.x;
    int w = tid >> 6, lane = tid & 63;
    f32x4 acc[2][5] = {};

    for (int kc = 0; kc < 8; ++kc) {
        int k0 = kc * 64;
        #pragma unroll
        for (int i = 0; i < 4; ++i) {                  // A: 1024 16B slots
            int s = tid + i * 256;
            int row = s >> 3, slot = s & 7;
            i32x4 v = *reinterpret_cast<const i32x4*>(Abf + (size_t)(m0 + row) * HIDDEN + k0 + slot * 8);
            *reinterpret_cast<i32x4*>(sA + row * 128 + ((slot ^ (row & 7)) * 16)) = v;
        }
        #pragma unroll
        for (int i = 0; i < 3; ++i) {                  // B: 640 slots
            int s = tid + i * 256;
            if (s < 640) {
                int row = s >> 3, slot = s & 7;
                i32x4 v = *reinterpret_cast<const i32x4*>(Btbf + (size_t)(n0 + row) * HIDDEN + k0 + slot * 8);
                *reinterpret_cast<i32x4*>(sB + row * 128 + ((slot ^ (row & 7)) * 16)) = v;
            }
        }
        __syncthreads();
        #pragma unroll
        for (int k2 = 0; k2 < 2; ++k2) {
            bf16x8 a[2], b[5];
            #pragma unroll
            for (int rf = 0; rf < 2; ++rf) {
                int row = w * 32 + rf * 16 + (lane & 15);
                int off = (k2 * 64 + (lane >> 4) * 16) ^ ((row & 7) << 4);
                a[rf] = *reinterpret_cast<const bf16x8*>(sA + row * 128 + off);
            }
            #pragma unroll
            for (int cf = 0; cf < 5; ++cf) {
                int row = cf * 16 + (lane & 15);
                int off = (k2 * 64 + (lane >> 4) * 16) ^ ((row & 7) << 4);
                b[cf] = *reinterpret_cast<const bf16x8*>(sB + row * 128 + off);
            }
            #pragma unroll
            for (int rf = 0; rf < 2; ++rf)
                #pragma unroll
                for (int cf = 0; cf < 5; ++cf)
                    acc[rf][cf] = __builtin_amdgcn_mfma_f32_16x16x32_bf16(a[rf], b[cf], acc[rf][cf], 0, 0, 0);
        }
        __syncthreads();
    }
    #pragma unroll
    for (int cf = 0; cf < 5; ++cf) {
        int col = n0 + cf * 16 + (lane & 15);
        float bv = bias[col];
        #pragma unroll
        for (int rf = 0; rf < 2; ++rf)
            #pragma unroll
            for (int r = 0; r < 4; ++r) {
                int row = m0 + w * 32 + rf * 16 + (lane >> 4) * 4 + r;
                Cout[(size_t)row * VOCAB + col] = acc[rf][cf][r] + bv;
            }
    }
}

// ---------------------------------------------------------------------------
__global__ void finalize_hc(const float* __restrict__ hfin, const float* __restrict__ cfin,
                            float* __restrict__ out) {
    int i = blockIdx.x * 256 + threadIdx.x;       // 0..65535
    size_t base = (size_t)M_ROWS * VOCAB;
    if (i < BATCH * HIDDEN)
        out[base + i] = hfin[i];
    else
        out[base + i] = cfin[i - BATCH * HIDDEN];
}

extern "C" void kernel_launch(void* const* d_in, const int* in_sizes, int n_in,
                              void* d_out, int out_size, void* d_ws, size_t ws_size,
                              hipStream_t stream) {
    (void)in_sizes; (void)n_in; (void)out_size; (void)ws_size;
    const int*   input_ = (const int*)  d_in[0];
    const float* Emb    = (const float*)d_in[1];
    const float* Wxi    = (const float*)d_in[2];
    const float* Whi    = (const float*)d_in[3];
    const float* bi     = (const float*)d_in[4];
    const float* Wxf    = (const float*)d_in[5];
    const float* Whf    = (const float*)d_in[6];
    const float* bf_    = (const float*)d_in[7];
    const float* Wxc    = (const float*)d_in[8];
    const float* Whc    = (const float*)d_in[9];
    const float* bc     = (const float*)d_in[10];
    const float* Wxo    = (const float*)d_in[11];
    const float* Who    = (const float*)d_in[12];
    const float* bo     = (const float*)d_in[13];
    const float* W      = (const float*)d_in[14];
    const float* b      = (const float*)d_in[15];
    float* out = (float*)d_out;

    char* ws = (char*)d_ws;
    float*          xg   = (float*)         (ws);                 // 67,108,864
    unsigned short* hsbf = (unsigned short*)(ws +  67108864);     //  8,388,608
    unsigned short* Wtbf = (unsigned short*)(ws +  75497472);     // 10,240,000
    unsigned short* WhT  = (unsigned short*)(ws +  85737472);     //  2,097,152
    float*          hfin = (float*)         (ws +  87834624);     //    131,072
    float*          cbuf = (float*)         (ws +  87965696);     //    131,072
    unsigned*       flags= (unsigned*)      (ws +  88096768);     //     16,384

    wt_convert<<<dim3(313, 16), dim3(32, 32), 0, stream>>>(W, Wtbf);
    wh_convert<<<dim3(16, 16, 4), dim3(32, 32), 0, stream>>>(Whi, Whf, Whc, Who, WhT);
    xproj<<<dim3(32, 64), 256, 0, stream>>>(input_, Emb, Wxi, Wxf, Wxc, Wxo,
                                            bi, bf_, bc, bo, xg);
    hipMemsetAsync(flags, 0, (size_t)T_STEPS * NBLK * 4, stream);

    {
        const float* xg_c = xg;
        const unsigned short* WhT_c = WhT;
        unsigned short* hsbf_p = hsbf;
        float* hfin_p = hfin; float* cbuf_p = cbuf; unsigned* flags_p = flags;
        void* args[] = { (void*)&xg_c, (void*)&WhT_c, (void*)&hsbf_p,
                         (void*)&hfin_p, (void*)&cbuf_p, (void*)&flags_p };
        hipLaunchCooperativeKernel((void*)lstm_scan, dim3(NBLK), dim3(512), args, 0, stream);
    }

    out_proj<<<dim3(125, 64), 256, 0, stream>>>(hsbf, Wtbf, b, out);
    finalize_hc<<<256, 256, 0, stream>>>(hfin, cbuf, out);
}

// Round 8
// 829.558 us; speedup vs baseline: 1.0551x; 1.0551x over previous
//
#include <hip/hip_runtime.h>
#include <stdint.h>

#define T_STEPS 128
#define BATCH   64
#define EMBED   256
#define HIDDEN  512
#define VOCAB   10000
#define M_ROWS  (T_STEPS*BATCH)   // 8192
#define NGATE   (4*HIDDEN)        // 2048
#define NBLK    32                // lstm worker blocks

typedef __attribute__((ext_vector_type(2))) float  f32x2;
typedef __attribute__((ext_vector_type(4))) float  f32x4;
typedef __attribute__((ext_vector_type(4))) int    i32x4;
typedef __attribute__((ext_vector_type(8))) __bf16 bf16x8;

static __device__ __forceinline__ unsigned short f32_to_bf16(float f) {
    union { float f; uint32_t u; } v; v.f = f;
    uint32_t u = v.u;
    return (unsigned short)((u + 0x7FFFu + ((u >> 16) & 1u)) >> 16);  // RNE
}
static __device__ __forceinline__ float sigf(float x) {
    return 1.f / (1.f + __expf(-x));
}
static __device__ __forceinline__ float tanhfast(float x) {
    float e = __expf(2.f * fminf(fmaxf(x, -15.f), 15.f));
    return (e - 1.f) / (e + 1.f);
}
// fused 2-lane cell update
static __device__ __forceinline__ void cell2(
    float pi0, float pi1, float pf0, float pf1, float pg0, float pg1,
    float po0, float po1, float& c0, float& c1, float& h0, float& h1) {
    float i0 = sigf(pi0), i1 = sigf(pi1);
    float f0 = sigf(pf0), f1 = sigf(pf1);
    float g0 = tanhfast(pg0), g1 = tanhfast(pg1);
    float o0 = sigf(po0), o1 = sigf(po1);
    c0 = f0 * c0 + i0 * g0;
    c1 = f1 * c1 + i1 * g1;
    h0 = o0 * tanhfast(c0);
    h1 = o1 * tanhfast(c1);
}

// IC-coherent (bypass L1+L2) primitives — the verified cross-XCD path.
static __device__ __forceinline__ i32x4 ld16ic(const void* p) {
    i32x4 r; asm volatile("global_load_dwordx4 %0, %1, off sc0 sc1" : "=v"(r) : "v"(p)); return r;
}
static __device__ __forceinline__ void st4ic(void* p, unsigned v) {
    asm volatile("global_store_dword %0, %1, off sc0 sc1" :: "v"(p), "v"(v) : "memory");
}

// ---------------------------------------------------------------------------
// Poison hsbf with 0xFFFFFFFF (bf16-NaN pair sentinel; |h|<1 never hits it).
// ---------------------------------------------------------------------------
__global__ void poison_hsbf(unsigned* __restrict__ p) {
    size_t i = (size_t)blockIdx.x * 256 + threadIdx.x;   // 524288 threads x 16B
    i32x4 v = { -1, -1, -1, -1 };
    asm volatile("global_store_dwordx4 %0, %1, off sc0 sc1"
                 :: "v"((char*)p + i * 16), "v"(v) : "memory");
}

// ---------------------------------------------------------------------------
// W [512][10000] f32  ->  Wt [10000][512] bf16   (tiled transpose + convert)
// ---------------------------------------------------------------------------
__global__ void wt_convert(const float* __restrict__ W, unsigned short* __restrict__ Wt) {
    __shared__ float tile[32][33];
    int n0 = blockIdx.x * 32;
    int k0 = blockIdx.y * 32;
    int tx = threadIdx.x, ty = threadIdx.y;
    int n = n0 + tx;
    if (n < VOCAB) tile[ty][tx] = W[(size_t)(k0 + ty) * VOCAB + n];
    __syncthreads();
    int nn = n0 + ty;
    if (nn < VOCAB) Wt[(size_t)nn * HIDDEN + k0 + tx] = f32_to_bf16(tile[tx][ty]);
}

// ---------------------------------------------------------------------------
// Wh_g [512 k][512 n] f32 -> WhT [4][512 n][512 k] bf16
// ---------------------------------------------------------------------------
__global__ void wh_convert(const float* __restrict__ Whi, const float* __restrict__ Whf,
                           const float* __restrict__ Whc, const float* __restrict__ Who,
                           unsigned short* __restrict__ WhT) {
    __shared__ float tile[32][33];
    int g = blockIdx.z;
    const float* Wg = (g == 0) ? Whi : (g == 1) ? Whf : (g == 2) ? Whc : Who;
    int n0 = blockIdx.x * 32, k0 = blockIdx.y * 32;
    int tx = threadIdx.x, ty = threadIdx.y;
    tile[ty][tx] = Wg[(size_t)(k0 + ty) * HIDDEN + n0 + tx];
    __syncthreads();
    WhT[((size_t)g * HIDDEN + n0 + ty) * HIDDEN + k0 + tx] = f32_to_bf16(tile[tx][ty]);
}

// ---------------------------------------------------------------------------
// xg[m][g*512+hc] = embeddings[input_[m]] @ W_xg + b_g   (fp32 tiled GEMM)
// ---------------------------------------------------------------------------
__global__ __launch_bounds__(256) void xproj(
    const int* __restrict__ idx, const float* __restrict__ Emb,
    const float* __restrict__ Wxi, const float* __restrict__ Wxf,
    const float* __restrict__ Wxc, const float* __restrict__ Wxo,
    const float* __restrict__ bi,  const float* __restrict__ bf_,
    const float* __restrict__ bc,  const float* __restrict__ bo,
    float* __restrict__ xg)
{
    __shared__ float At[32][132];   // [k][m], padded
    __shared__ float Bt[32][68];    // [k][n], padded
    int cb = blockIdx.x;            // 0..31 (8 col-blocks per gate)
    int rb = blockIdx.y;            // 0..63
    int g  = cb >> 3;
    int hc0 = (cb & 7) * 64;
    const float* Wg = (g == 0) ? Wxi : (g == 1) ? Wxf : (g == 2) ? Wxc : Wxo;
    const float* bg = (g == 0) ? bi  : (g == 1) ? bf_ : (g == 2) ? bc  : bo;
    int m0 = rb * 128;
    int tid = threadIdx.x;
    int tr = tid >> 4, tc = tid & 15;
    float acc[8][4] = {};

    for (int kc = 0; kc < EMBED; kc += 32) {
        #pragma unroll
        for (int i = 0; i < 4; ++i) {
            int s = tid + i * 256;            // 0..1023
            int row = s >> 3, k4 = s & 7;
            int er = idx[m0 + row];
            f32x4 v = *reinterpret_cast<const f32x4*>(Emb + (size_t)er * EMBED + kc + k4 * 4);
            #pragma unroll
            for (int j = 0; j < 4; ++j) At[k4 * 4 + j][row] = v[j];
        }
        #pragma unroll
        for (int i = 0; i < 2; ++i) {
            int s = tid + i * 256;            // 0..511
            int k = s >> 4, c4 = s & 15;
            f32x4 v = *reinterpret_cast<const f32x4*>(Wg + (size_t)(kc + k) * HIDDEN + hc0 + c4 * 4);
            *reinterpret_cast<f32x4*>(&Bt[k][c4 * 4]) = v;
        }
        __syncthreads();
        #pragma unroll 8
        for (int k = 0; k < 32; ++k) {
            f32x4 a0 = *reinterpret_cast<const f32x4*>(&At[k][tr * 8]);
            f32x4 a1 = *reinterpret_cast<const f32x4*>(&At[k][tr * 8 + 4]);
            f32x4 b4 = *reinterpret_cast<const f32x4*>(&Bt[k][tc * 4]);
            float av[8] = {a0[0],a0[1],a0[2],a0[3],a1[0],a1[1],a1[2],a1[3]};
            #pragma unroll
            for (int i = 0; i < 8; ++i)
                #pragma unroll
                for (int j = 0; j < 4; ++j)
                    acc[i][j] += av[i] * b4[j];
        }
        __syncthreads();
    }
    f32x4 bb = *reinterpret_cast<const f32x4*>(bg + hc0 + tc * 4);
    #pragma unroll
    for (int i = 0; i < 8; ++i) {
        int row = m0 + tr * 8 + i;
        f32x4 o;
        #pragma unroll
        for (int j = 0; j < 4; ++j) o[j] = acc[i][j] + bb[j];
        *reinterpret_cast<f32x4*>(xg + (size_t)row * NGATE + g * HIDDEN + hc0 + tc * 4) = o;
    }
}

// ---------------------------------------------------------------------------
// Persistent LSTM scan, 32 blocks x 512 threads, batch-split DOUBLE PIPELINE:
// rows 0-31 (group A) and 32-63 (group B) are independent chains; the block
// alternates A/B phases so each group's IC publication latency hides under
// the other group's compute. Sentinel dataflow (R5-proven): hsbf pre-poisoned
// 0xFFFFFFFF; publish = sc0sc1 store; consume = sc0sc1 poll-load.
// ---------------------------------------------------------------------------
__global__ __launch_bounds__(512) void lstm_scan(
    const float* __restrict__ xg,
    const unsigned short* __restrict__ WhT,   // [4][512][512] bf16
    unsigned short* hsbf,                     // [128][64][512] bf16 (poisoned)
    float* __restrict__ hfin, float* __restrict__ cfin)
{
    __shared__ __align__(16) unsigned char hstage[32768];  // 32 x 512 bf16, swizzled
    __shared__ float P_lds[4][32][17];                     // padded (bank)
    const int tid  = threadIdx.x;
    const int bx   = blockIdx.x;        // 0..31
    const int hc0  = bx * 16;
    const int lane = tid & 63, w = tid >> 6;
    const int wm   = w >> 2, wg = w & 3;     // row-half 0..1, gate 0..3

    // ---- preload Wh slice: wave (.,wg) lane l: col hc0+(l&15), 8 k per kstep
    bf16x8 breg[16];
    {
        const unsigned short* base =
            WhT + ((size_t)wg * HIDDEN + hc0 + (lane & 15)) * HIDDEN + (lane >> 4) * 8;
        #pragma unroll
        for (int ks = 0; ks < 16; ++ks)
            breg[ks] = *reinterpret_cast<const bf16x8*>(base + ks * 32);
    }

    // ---- update-thread mapping (tid < 256): (row-in-group, hc pair)
    const int ub  = tid >> 3;          // 0..31
    const int uhp = tid & 7;           // 0..7
    const int uhc = hc0 + uhp * 2;
    float cA0 = 0.f, cA1 = 0.f, cB0 = 0.f, cB1 = 0.f;
    f32x2 xvA[4], xvB[4];
    if (tid < 256) {
        const float* xrA = xg + (size_t)(0 * 32 + ub) * NGATE + uhc;
        const float* xrB = xg + (size_t)(1 * 32 + ub) * NGATE + uhc;
        #pragma unroll
        for (int g = 0; g < 4; ++g) {
            xvA[g] = *reinterpret_cast<const f32x2*>(xrA + g * HIDDEN);
            xvB[g] = *reinterpret_cast<const f32x2*>(xrB + g * HIDDEN);
        }
    }

    unsigned* hs32 = reinterpret_cast<unsigned*>(hsbf);

#define CHK(R) { mx = (mx > (unsigned)R[0]) ? mx : (unsigned)R[0]; \
                 mx = (mx > (unsigned)R[1]) ? mx : (unsigned)R[1]; \
                 mx = (mx > (unsigned)R[2]) ? mx : (unsigned)R[2]; \
                 mx = (mx > (unsigned)R[3]) ? mx : (unsigned)R[3]; }
#define STLDS(R, I) { int s16 = (I) * 512 + tid; int row = s16 >> 6, sl = s16 & 63; \
        *reinterpret_cast<i32x4*>(hstage + row * 1024 + ((sl ^ (row & 7)) << 4)) = R; }

    // ---- update + publish + x-prefetch for one group at step TT
#define GROUP_UPDATE(G, XV, C0, C1, TT)                                         \
    if (tid < 256) {                                                            \
        int hp2 = uhp * 2;                                                      \
        float h0, h1;                                                           \
        cell2(P_lds[0][ub][hp2] + XV[0][0], P_lds[0][ub][hp2+1] + XV[0][1],     \
              P_lds[1][ub][hp2] + XV[1][0], P_lds[1][ub][hp2+1] + XV[1][1],     \
              P_lds[2][ub][hp2] + XV[2][0], P_lds[2][ub][hp2+1] + XV[2][1],     \
              P_lds[3][ub][hp2] + XV[3][0], P_lds[3][ub][hp2+1] + XV[3][1],     \
              C0, C1, h0, h1);                                                  \
        unsigned hp = ((unsigned)f32_to_bf16(h1) << 16) | (unsigned)f32_to_bf16(h0); \
        st4ic(hs32 + (size_t)(TT) * 16384 + ((G) * 32 + ub) * 256 + (uhc >> 1), hp); \
        if ((TT) == T_STEPS - 1) {                                              \
            f32x2 hv = { h0, h1 };                                              \
            *reinterpret_cast<f32x2*>(hfin + (size_t)((G) * 32 + ub) * HIDDEN + uhc) = hv; \
        } else {                                                                \
            const float* xr = xg + (size_t)(((TT) + 1) * BATCH + (G) * 32 + ub) * NGATE + uhc; \
            _Pragma("unroll")                                                   \
            for (int g = 0; g < 4; ++g)                                         \
                XV[g] = *reinterpret_cast<const f32x2*>(xr + g * HIDDEN);       \
        }                                                                       \
    }

    // ---- full phase: poll h_{TT-1}(G), stage, MFMA, P-exchange, update
#define GROUP_PHASE(G, XV, C0, C1, TT)                                          \
    {                                                                           \
        f32x4 acc = {0.f, 0.f, 0.f, 0.f};                                       \
        {                                                                       \
            const char* hb = (const char*)hsbf + (size_t)((TT) - 1) * 65536 + (G) * 32768; \
            i32x4 q0, q1, q2, q3;                                               \
            for (int rnd = 0; rnd < (1 << 16); ++rnd) {                         \
                q0 = ld16ic(hb + (size_t)(0 * 512 + tid) * 16);                 \
                q1 = ld16ic(hb + (size_t)(1 * 512 + tid) * 16);                 \
                q2 = ld16ic(hb + (size_t)(2 * 512 + tid) * 16);                 \
                q3 = ld16ic(hb + (size_t)(3 * 512 + tid) * 16);                 \
                asm volatile("s_waitcnt vmcnt(0)"                               \
                    : "+v"(q0), "+v"(q1), "+v"(q2), "+v"(q3));                  \
                unsigned mx = 0u;                                               \
                CHK(q0) CHK(q1) CHK(q2) CHK(q3)                                 \
                if (mx != 0xFFFFFFFFu) break;                                   \
                __builtin_amdgcn_s_sleep(1);                                    \
            }                                                                   \
            __builtin_amdgcn_sched_barrier(0);                                  \
            STLDS(q0, 0) STLDS(q1, 1) STLDS(q2, 2) STLDS(q3, 3)                 \
        }                                                                       \
        __syncthreads();   /* staging ready; fences prev-phase P reads */       \
        {                                                                       \
            const int rr = wm * 16 + (lane & 15);                               \
            _Pragma("unroll")                                                   \
            for (int ks = 0; ks < 16; ++ks) {                                   \
                int sl = ks * 4 + (lane >> 4);                                  \
                bf16x8 a = *reinterpret_cast<const bf16x8*>(                    \
                    hstage + rr * 1024 + ((sl ^ (rr & 7)) << 4));               \
                acc = __builtin_amdgcn_mfma_f32_16x16x32_bf16(a, breg[ks], acc, 0, 0, 0); \
            }                                                                   \
        }                                                                       \
        {                                                                       \
            int colr = lane & 15, rowb = (lane >> 4) * 4;                       \
            _Pragma("unroll")                                                   \
            for (int r = 0; r < 4; ++r)                                         \
                P_lds[wg][wm * 16 + rowb + r][colr] = acc[r];                   \
        }                                                                       \
        __syncthreads();                                                        \
        GROUP_UPDATE(G, XV, C0, C1, TT)                                         \
    }

    // ---- t = 0: no recurrence (P = 0, c = 0) — registers only, no syncs
    if (tid < 256) {
        int hp2 = uhp * 2; (void)hp2;
        float h0, h1;
        cell2(xvA[0][0], xvA[0][1], xvA[1][0], xvA[1][1],
              xvA[2][0], xvA[2][1], xvA[3][0], xvA[3][1], cA0, cA1, h0, h1);
        unsigned hp = ((unsigned)f32_to_bf16(h1) << 16) | (unsigned)f32_to_bf16(h0);
        st4ic(hs32 + (size_t)(0 * 32 + ub) * 256 + (uhc >> 1), hp);
        const float* xr = xg + (size_t)(1 * BATCH + 0 * 32 + ub) * NGATE + uhc;
        #pragma unroll
        for (int g = 0; g < 4; ++g)
            xvA[g] = *reinterpret_cast<const f32x2*>(xr + g * HIDDEN);

        cell2(xvB[0][0], xvB[0][1], xvB[1][0], xvB[1][1],
              xvB[2][0], xvB[2][1], xvB[3][0], xvB[3][1], cB0, cB1, h0, h1);
        hp = ((unsigned)f32_to_bf16(h1) << 16) | (unsigned)f32_to_bf16(h0);
        st4ic(hs32 + (size_t)(1 * 32 + ub) * 256 + (uhc >> 1), hp);
        xr = xg + (size_t)(1 * BATCH + 1 * 32 + ub) * NGATE + uhc;
        #pragma unroll
        for (int g = 0; g < 4; ++g)
            xvB[g] = *reinterpret_cast<const f32x2*>(xr + g * HIDDEN);
    }

    for (int t = 1; t < T_STEPS; ++t) {
        GROUP_PHASE(0, xvA, cA0, cA1, t)
        GROUP_PHASE(1, xvB, cB0, cB1, t)
    }
#undef GROUP_PHASE
#undef GROUP_UPDATE
#undef STLDS
#undef CHK

    // ---- final c (both groups)
    if (tid < 256) {
        f32x2 cvA = { cA0, cA1 };
        f32x2 cvB = { cB0, cB1 };
        *reinterpret_cast<f32x2*>(cfin + (size_t)(0 * 32 + ub) * HIDDEN + uhc) = cvA;
        *reinterpret_cast<f32x2*>(cfin + (size_t)(1 * 32 + ub) * HIDDEN + uhc) = cvB;
    }
}

// ---------------------------------------------------------------------------
// out = hs_bf16 [8192,512] @ W_bf16^T [10000,512] + b   (bf16 MFMA, f32 acc)
// ---------------------------------------------------------------------------
__global__ __launch_bounds__(256) void out_proj(
    const unsigned short* __restrict__ Abf,   // [8192][512]
    const unsigned short* __restrict__ Btbf,  // [10000][512]
    const float* __restrict__ bias,           // [10000]
    float* __restrict__ Cout)                 // [8192][10000] f32
{
    __shared__ __align__(16) char sA[128 * 128];  // 128 rows x 64 bf16
    __shared__ __align__(16) char sB[80 * 128];   // 80 rows x 64 bf16
    int n0 = blockIdx.x * 80;
    int m0 = blockIdx.y * 128;
    int tid = threadIdx.x;
    int w = tid >> 6, lane = tid & 63;
    f32x4 acc[2][5] = {};

    for (int kc = 0; kc < 8; ++kc) {
        int k0 = kc * 64;
        #pragma unroll
        for (int i = 0; i < 4; ++i) {                  // A: 1024 16B slots
            int s = tid + i * 256;
            int row = s >> 3, slot = s & 7;
            i32x4 v = *reinterpret_cast<const i32x4*>(Abf + (size_t)(m0 + row) * HIDDEN + k0 + slot * 8);
            *reinterpret_cast<i32x4*>(sA + row * 128 + ((slot ^ (row & 7)) * 16)) = v;
        }
        #pragma unroll
        for (int i = 0; i < 3; ++i) {                  // B: 640 slots
            int s = tid + i * 256;
            if (s < 640) {
                int row = s >> 3, slot = s & 7;
                i32x4 v = *reinterpret_cast<const i32x4*>(Btbf + (size_t)(n0 + row) * HIDDEN + k0 + slot * 8);
                *reinterpret_cast<i32x4*>(sB + row * 128 + ((slot ^ (row & 7)) * 16)) = v;
            }
        }
        __syncthreads();
        #pragma unroll
        for (int k2 = 0; k2 < 2; ++k2) {
            bf16x8 a[2], b[5];
            #pragma unroll
            for (int rf = 0; rf < 2; ++rf) {
                int row = w * 32 + rf * 16 + (lane & 15);
                int off = (k2 * 64 + (lane >> 4) * 16) ^ ((row & 7) << 4);
                a[rf] = *reinterpret_cast<const bf16x8*>(sA + row * 128 + off);
            }
            #pragma unroll
            for (int cf = 0; cf < 5; ++cf) {
                int row = cf * 16 + (lane & 15);
                int off = (k2 * 64 + (lane >> 4) * 16) ^ ((row & 7) << 4);
                b[cf] = *reinterpret_cast<const bf16x8*>(sB + row * 128 + off);
            }
            #pragma unroll
            for (int rf = 0; rf < 2; ++rf)
                #pragma unroll
                for (int cf = 0; cf < 5; ++cf)
                    acc[rf][cf] = __builtin_amdgcn_mfma_f32_16x16x32_bf16(a[rf], b[cf], acc[rf][cf], 0, 0, 0);
        }
        __syncthreads();
    }
    #pragma unroll
    for (int cf = 0; cf < 5; ++cf) {
        int col = n0 + cf * 16 + (lane & 15);
        float bv = bias[col];
        #pragma unroll
        for (int rf = 0; rf < 2; ++rf)
            #pragma unroll
            for (int r = 0; r < 4; ++r) {
                int row = m0 + w * 32 + rf * 16 + (lane >> 4) * 4 + r;
                Cout[(size_t)row * VOCAB + col] = acc[rf][cf][r] + bv;
            }
    }
}

// ---------------------------------------------------------------------------
__global__ void finalize_hc(const float* __restrict__ hfin, const float* __restrict__ cfin,
                            float* __restrict__ out) {
    int i = blockIdx.x * 256 + threadIdx.x;       // 0..65535
    size_t base = (size_t)M_ROWS * VOCAB;
    if (i < BATCH * HIDDEN)
        out[base + i] = hfin[i];
    else
        out[base + i] = cfin[i - BATCH * HIDDEN];
}

extern "C" void kernel_launch(void* const* d_in, const int* in_sizes, int n_in,
                              void* d_out, int out_size, void* d_ws, size_t ws_size,
                              hipStream_t stream) {
    (void)in_sizes; (void)n_in; (void)out_size; (void)ws_size;
    const int*   input_ = (const int*)  d_in[0];
    const float* Emb    = (const float*)d_in[1];
    const float* Wxi    = (const float*)d_in[2];
    const float* Whi    = (const float*)d_in[3];
    const float* bi     = (const float*)d_in[4];
    const float* Wxf    = (const float*)d_in[5];
    const float* Whf    = (const float*)d_in[6];
    const float* bf_    = (const float*)d_in[7];
    const float* Wxc    = (const float*)d_in[8];
    const float* Whc    = (const float*)d_in[9];
    const float* bc     = (const float*)d_in[10];
    const float* Wxo    = (const float*)d_in[11];
    const float* Who    = (const float*)d_in[12];
    const float* bo     = (const float*)d_in[13];
    const float* W      = (const float*)d_in[14];
    const float* b      = (const float*)d_in[15];
    float* out = (float*)d_out;

    char* ws = (char*)d_ws;
    float*          xg   = (float*)         (ws);                 // 67,108,864
    unsigned short* hsbf = (unsigned short*)(ws +  67108864);     //  8,388,608
    unsigned short* Wtbf = (unsigned short*)(ws +  75497472);     // 10,240,000
    unsigned short* WhT  = (unsigned short*)(ws +  85737472);     //  2,097,152
    float*          hfin = (float*)         (ws +  87834624);     //    131,072
    float*          cbuf = (float*)         (ws +  87965696);     //    131,072

    poison_hsbf<<<2048, 256, 0, stream>>>((unsigned*)hsbf);
    wt_convert<<<dim3(313, 16), dim3(32, 32), 0, stream>>>(W, Wtbf);
    wh_convert<<<dim3(16, 16, 4), dim3(32, 32), 0, stream>>>(Whi, Whf, Whc, Who, WhT);
    xproj<<<dim3(32, 64), 256, 0, stream>>>(input_, Emb, Wxi, Wxf, Wxc, Wxo,
                                            bi, bf_, bc, bo, xg);

    {
        const float* xg_c = xg;
        const unsigned short* WhT_c = WhT;
        unsigned short* hsbf_p = hsbf;
        float* hfin_p = hfin; float* cbuf_p = cbuf;
        void* args[] = { (void*)&xg_c, (void*)&WhT_c, (void*)&hsbf_p,
                         (void*)&hfin_p, (void*)&cbuf_p };
        hipLaunchCooperativeKernel((void*)lstm_scan, dim3(NBLK), dim3(512), args, 0, stream);
    }

    out_proj<<<dim3(125, 64), 256, 0, stream>>>(hsbf, Wtbf, b, out);
    finalize_hc<<<256, 256, 0, stream>>>(hfin, cbuf, out);
}

// Round 9
// 812.745 us; speedup vs baseline: 1.0769x; 1.0207x over previous
//
#include <hip/hip_runtime.h>
#include <stdint.h>

#define T_STEPS 128
#define BATCH   64
#define EMBED   256
#define HIDDEN  512
#define VOCAB   10000
#define M_ROWS  (T_STEPS*BATCH)   // 8192
#define NGATE   (4*HIDDEN)        // 2048
#define NBLK    32                // lstm worker blocks
#define NLAUNCH 256               // total cooperative blocks
#define NGEMM   (NLAUNCH-NBLK)    // 224 drafting GEMM blocks
#define NTILE_M 64                // 8192/128
#define NTILE_N 125               // 10000/80

typedef __attribute__((ext_vector_type(2))) float  f32x2;
typedef __attribute__((ext_vector_type(4))) float  f32x4;
typedef __attribute__((ext_vector_type(4))) int    i32x4;
typedef __attribute__((ext_vector_type(8))) __bf16 bf16x8;

static __device__ __forceinline__ unsigned short f32_to_bf16(float f) {
    union { float f; uint32_t u; } v; v.f = f;
    uint32_t u = v.u;
    return (unsigned short)((u + 0x7FFFu + ((u >> 16) & 1u)) >> 16);  // RNE
}
static __device__ __forceinline__ float sigf(float x) {
    return 1.f / (1.f + __expf(-x));
}
static __device__ __forceinline__ float tanhfast(float x) {
    float e = __expf(2.f * fminf(fmaxf(x, -15.f), 15.f));
    return (e - 1.f) / (e + 1.f);
}
static __device__ __forceinline__ void cell2(
    float pi0, float pi1, float pf0, float pf1, float pg0, float pg1,
    float po0, float po1, float& c0, float& c1, float& h0, float& h1) {
    float i0 = sigf(pi0), i1 = sigf(pi1);
    float f0 = sigf(pf0), f1 = sigf(pf1);
    float g0 = tanhfast(pg0), g1 = tanhfast(pg1);
    float o0 = sigf(po0), o1 = sigf(po1);
    c0 = f0 * c0 + i0 * g0;
    c1 = f1 * c1 + i1 * g1;
    h0 = o0 * tanhfast(c0);
    h1 = o1 * tanhfast(c1);
}

// IC-coherent (bypass L1+L2) primitives — the verified cross-XCD path.
static __device__ __forceinline__ i32x4 ld16ic(const void* p) {
    i32x4 r; asm volatile("global_load_dwordx4 %0, %1, off sc0 sc1" : "=v"(r) : "v"(p)); return r;
}
static __device__ __forceinline__ unsigned ld4ic(const void* p) {
    unsigned r; asm volatile("global_load_dword %0, %1, off sc0 sc1" : "=v"(r) : "v"(p)); return r;
}
static __device__ __forceinline__ void st4ic(void* p, unsigned v) {
    asm volatile("global_store_dword %0, %1, off sc0 sc1" :: "v"(p), "v"(v) : "memory");
}

// ---------------------------------------------------------------------------
__global__ void poison_hsbf(unsigned* __restrict__ p) {
    size_t i = (size_t)blockIdx.x * 256 + threadIdx.x;   // 524288 threads x 16B
    i32x4 v = { -1, -1, -1, -1 };
    asm volatile("global_store_dwordx4 %0, %1, off sc0 sc1"
                 :: "v"((char*)p + i * 16), "v"(v) : "memory");
}

// ---------------------------------------------------------------------------
__global__ void wt_convert(const float* __restrict__ W, unsigned short* __restrict__ Wt) {
    __shared__ float tile[32][33];
    int n0 = blockIdx.x * 32;
    int k0 = blockIdx.y * 32;
    int tx = threadIdx.x, ty = threadIdx.y;
    int n = n0 + tx;
    if (n < VOCAB) tile[ty][tx] = W[(size_t)(k0 + ty) * VOCAB + n];
    __syncthreads();
    int nn = n0 + ty;
    if (nn < VOCAB) Wt[(size_t)nn * HIDDEN + k0 + tx] = f32_to_bf16(tile[tx][ty]);
}

// ---------------------------------------------------------------------------
__global__ void wh_convert(const float* __restrict__ Whi, const float* __restrict__ Whf,
                           const float* __restrict__ Whc, const float* __restrict__ Who,
                           unsigned short* __restrict__ WhT) {
    __shared__ float tile[32][33];
    int g = blockIdx.z;
    const float* Wg = (g == 0) ? Whi : (g == 1) ? Whf : (g == 2) ? Whc : Who;
    int n0 = blockIdx.x * 32, k0 = blockIdx.y * 32;
    int tx = threadIdx.x, ty = threadIdx.y;
    tile[ty][tx] = Wg[(size_t)(k0 + ty) * HIDDEN + n0 + tx];
    __syncthreads();
    WhT[((size_t)g * HIDDEN + n0 + ty) * HIDDEN + k0 + tx] = f32_to_bf16(tile[tx][ty]);
}

// ---------------------------------------------------------------------------
__global__ __launch_bounds__(256) void xproj(
    const int* __restrict__ idx, const float* __restrict__ Emb,
    const float* __restrict__ Wxi, const float* __restrict__ Wxf,
    const float* __restrict__ Wxc, const float* __restrict__ Wxo,
    const float* __restrict__ bi,  const float* __restrict__ bf_,
    const float* __restrict__ bc,  const float* __restrict__ bo,
    float* __restrict__ xg)
{
    __shared__ float At[32][132];   // [k][m], padded
    __shared__ float Bt[32][68];    // [k][n], padded
    int cb = blockIdx.x;            // 0..31 (8 col-blocks per gate)
    int rb = blockIdx.y;            // 0..63
    int g  = cb >> 3;
    int hc0 = (cb & 7) * 64;
    const float* Wg = (g == 0) ? Wxi : (g == 1) ? Wxf : (g == 2) ? Wxc : Wxo;
    const float* bg = (g == 0) ? bi  : (g == 1) ? bf_ : (g == 2) ? bc  : bo;
    int m0 = rb * 128;
    int tid = threadIdx.x;
    int tr = tid >> 4, tc = tid & 15;
    float acc[8][4] = {};

    for (int kc = 0; kc < EMBED; kc += 32) {
        #pragma unroll
        for (int i = 0; i < 4; ++i) {
            int s = tid + i * 256;            // 0..1023
            int row = s >> 3, k4 = s & 7;
            int er = idx[m0 + row];
            f32x4 v = *reinterpret_cast<const f32x4*>(Emb + (size_t)er * EMBED + kc + k4 * 4);
            #pragma unroll
            for (int j = 0; j < 4; ++j) At[k4 * 4 + j][row] = v[j];
        }
        #pragma unroll
        for (int i = 0; i < 2; ++i) {
            int s = tid + i * 256;            // 0..511
            int k = s >> 4, c4 = s & 15;
            f32x4 v = *reinterpret_cast<const f32x4*>(Wg + (size_t)(kc + k) * HIDDEN + hc0 + c4 * 4);
            *reinterpret_cast<f32x4*>(&Bt[k][c4 * 4]) = v;
        }
        __syncthreads();
        #pragma unroll 8
        for (int k = 0; k < 32; ++k) {
            f32x4 a0 = *reinterpret_cast<const f32x4*>(&At[k][tr * 8]);
            f32x4 a1 = *reinterpret_cast<const f32x4*>(&At[k][tr * 8 + 4]);
            f32x4 b4 = *reinterpret_cast<const f32x4*>(&Bt[k][tc * 4]);
            float av[8] = {a0[0],a0[1],a0[2],a0[3],a1[0],a1[1],a1[2],a1[3]};
            #pragma unroll
            for (int i = 0; i < 8; ++i)
                #pragma unroll
                for (int j = 0; j < 4; ++j)
                    acc[i][j] += av[i] * b4[j];
        }
        __syncthreads();
    }
    f32x4 bb = *reinterpret_cast<const f32x4*>(bg + hc0 + tc * 4);
    #pragma unroll
    for (int i = 0; i < 8; ++i) {
        int row = m0 + tr * 8 + i;
        f32x4 o;
        #pragma unroll
        for (int j = 0; j < 4; ++j) o[j] = acc[i][j] + bb[j];
        *reinterpret_cast<f32x4*>(xg + (size_t)row * NGATE + g * HIDDEN + hc0 + tc * 4) = o;
    }
}

// ---------------------------------------------------------------------------
// FUSED persistent kernel, 256 blocks x 512 threads (cooperative):
//  blocks 0..31   : R8 batch-split double-pipeline LSTM scan (unchanged).
//  blocks 32..255 : persistent out_proj GEMM workers DRAFTING behind the
//                   scan — per 128x80 tile, sentinel-poll the A rows via IC
//                   (canary + block vote), then swizzled bf16 MFMA.
// ---------------------------------------------------------------------------
__global__ __launch_bounds__(512) void lstm_fused(
    const float* __restrict__ xg,
    const unsigned short* __restrict__ WhT,   // [4][512][512] bf16
    unsigned short* hsbf,                     // [128][64][512] bf16 (poisoned)
    float* __restrict__ hfin, float* __restrict__ cfin,
    const unsigned short* __restrict__ Btbf,  // [10000][512] bf16
    const float* __restrict__ bias,           // [10000]
    float* __restrict__ Cout)                 // [8192][10000] f32
{
    __shared__ __align__(16) unsigned char smem[41472];
    const int tid = threadIdx.x;

    if (blockIdx.x < NBLK) {
        // =================== SCAN ROLE (R8, proven) ========================
        unsigned char* hstage = smem;                               // 32KB
        auto P_lds = reinterpret_cast<float (*)[32][17]>(smem + 32768);
        const int bx   = blockIdx.x;
        const int hc0  = bx * 16;
        const int lane = tid & 63, w = tid >> 6;
        const int wm   = w >> 2, wg = w & 3;

        bf16x8 breg[16];
        {
            const unsigned short* base =
                WhT + ((size_t)wg * HIDDEN + hc0 + (lane & 15)) * HIDDEN + (lane >> 4) * 8;
            #pragma unroll
            for (int ks = 0; ks < 16; ++ks)
                breg[ks] = *reinterpret_cast<const bf16x8*>(base + ks * 32);
        }

        const int ub  = tid >> 3;          // 0..31 (tid<256)
        const int uhp = tid & 7;
        const int uhc = hc0 + uhp * 2;
        float cA0 = 0.f, cA1 = 0.f, cB0 = 0.f, cB1 = 0.f;
        f32x2 xvA[4], xvB[4];
        if (tid < 256) {
            const float* xrA = xg + (size_t)(0 * 32 + ub) * NGATE + uhc;
            const float* xrB = xg + (size_t)(1 * 32 + ub) * NGATE + uhc;
            #pragma unroll
            for (int g = 0; g < 4; ++g) {
                xvA[g] = *reinterpret_cast<const f32x2*>(xrA + g * HIDDEN);
                xvB[g] = *reinterpret_cast<const f32x2*>(xrB + g * HIDDEN);
            }
        }
        unsigned* hs32 = reinterpret_cast<unsigned*>(hsbf);

#define CHK(R) { mx = (mx > (unsigned)R[0]) ? mx : (unsigned)R[0]; \
                 mx = (mx > (unsigned)R[1]) ? mx : (unsigned)R[1]; \
                 mx = (mx > (unsigned)R[2]) ? mx : (unsigned)R[2]; \
                 mx = (mx > (unsigned)R[3]) ? mx : (unsigned)R[3]; }
#define STLDS(R, I) { int s16 = (I) * 512 + tid; int row = s16 >> 6, sl = s16 & 63; \
        *reinterpret_cast<i32x4*>(hstage + row * 1024 + ((sl ^ (row & 7)) << 4)) = R; }

#define GROUP_UPDATE(G, XV, C0, C1, TT)                                         \
    if (tid < 256) {                                                            \
        int hp2 = uhp * 2;                                                      \
        float h0, h1;                                                           \
        cell2(P_lds[0][ub][hp2] + XV[0][0], P_lds[0][ub][hp2+1] + XV[0][1],     \
              P_lds[1][ub][hp2] + XV[1][0], P_lds[1][ub][hp2+1] + XV[1][1],     \
              P_lds[2][ub][hp2] + XV[2][0], P_lds[2][ub][hp2+1] + XV[2][1],     \
              P_lds[3][ub][hp2] + XV[3][0], P_lds[3][ub][hp2+1] + XV[3][1],     \
              C0, C1, h0, h1);                                                  \
        unsigned hp = ((unsigned)f32_to_bf16(h1) << 16) | (unsigned)f32_to_bf16(h0); \
        st4ic(hs32 + (size_t)(TT) * 16384 + ((G) * 32 + ub) * 256 + (uhc >> 1), hp); \
        if ((TT) == T_STEPS - 1) {                                              \
            f32x2 hv = { h0, h1 };                                              \
            *reinterpret_cast<f32x2*>(hfin + (size_t)((G) * 32 + ub) * HIDDEN + uhc) = hv; \
        } else {                                                                \
            const float* xr = xg + (size_t)(((TT) + 1) * BATCH + (G) * 32 + ub) * NGATE + uhc; \
            _Pragma("unroll")                                                   \
            for (int g = 0; g < 4; ++g)                                         \
                XV[g] = *reinterpret_cast<const f32x2*>(xr + g * HIDDEN);       \
        }                                                                       \
    }

#define GROUP_PHASE(G, XV, C0, C1, TT)                                          \
    {                                                                           \
        f32x4 acc = {0.f, 0.f, 0.f, 0.f};                                       \
        {                                                                       \
            const char* hb = (const char*)hsbf + (size_t)((TT) - 1) * 65536 + (G) * 32768; \
            i32x4 q0, q1, q2, q3;                                               \
            for (int rnd = 0; rnd < (1 << 16); ++rnd) {                         \
                q0 = ld16ic(hb + (size_t)(0 * 512 + tid) * 16);                 \
                q1 = ld16ic(hb + (size_t)(1 * 512 + tid) * 16);                 \
                q2 = ld16ic(hb + (size_t)(2 * 512 + tid) * 16);                 \
                q3 = ld16ic(hb + (size_t)(3 * 512 + tid) * 16);                 \
                asm volatile("s_waitcnt vmcnt(0)"                               \
                    : "+v"(q0), "+v"(q1), "+v"(q2), "+v"(q3));                  \
                unsigned mx = 0u;                                               \
                CHK(q0) CHK(q1) CHK(q2) CHK(q3)                                 \
                if (mx != 0xFFFFFFFFu) break;                                   \
                __builtin_amdgcn_s_sleep(1);                                    \
            }                                                                   \
            __builtin_amdgcn_sched_barrier(0);                                  \
            STLDS(q0, 0) STLDS(q1, 1) STLDS(q2, 2) STLDS(q3, 3)                 \
        }                                                                       \
        __syncthreads();                                                        \
        {                                                                       \
            const int rr = wm * 16 + (lane & 15);                               \
            _Pragma("unroll")                                                   \
            for (int ks = 0; ks < 16; ++ks) {                                   \
                int sl = ks * 4 + (lane >> 4);                                  \
                bf16x8 a = *reinterpret_cast<const bf16x8*>(                    \
                    hstage + rr * 1024 + ((sl ^ (rr & 7)) << 4));               \
                acc = __builtin_amdgcn_mfma_f32_16x16x32_bf16(a, breg[ks], acc, 0, 0, 0); \
            }                                                                   \
        }                                                                       \
        {                                                                       \
            int colr = lane & 15, rowb = (lane >> 4) * 4;                       \
            _Pragma("unroll")                                                   \
            for (int r = 0; r < 4; ++r)                                         \
                P_lds[wg][wm * 16 + rowb + r][colr] = acc[r];                   \
        }                                                                       \
        __syncthreads();                                                        \
        GROUP_UPDATE(G, XV, C0, C1, TT)                                         \
    }

        // t = 0: registers only
        if (tid < 256) {
            float h0, h1;
            cell2(xvA[0][0], xvA[0][1], xvA[1][0], xvA[1][1],
                  xvA[2][0], xvA[2][1], xvA[3][0], xvA[3][1], cA0, cA1, h0, h1);
            unsigned hp = ((unsigned)f32_to_bf16(h1) << 16) | (unsigned)f32_to_bf16(h0);
            st4ic(hs32 + (size_t)(0 * 32 + ub) * 256 + (uhc >> 1), hp);
            const float* xr = xg + (size_t)(1 * BATCH + 0 * 32 + ub) * NGATE + uhc;
            #pragma unroll
            for (int g = 0; g < 4; ++g)
                xvA[g] = *reinterpret_cast<const f32x2*>(xr + g * HIDDEN);

            cell2(xvB[0][0], xvB[0][1], xvB[1][0], xvB[1][1],
                  xvB[2][0], xvB[2][1], xvB[3][0], xvB[3][1], cB0, cB1, h0, h1);
            hp = ((unsigned)f32_to_bf16(h1) << 16) | (unsigned)f32_to_bf16(h0);
            st4ic(hs32 + (size_t)(1 * 32 + ub) * 256 + (uhc >> 1), hp);
            xr = xg + (size_t)(1 * BATCH + 1 * 32 + ub) * NGATE + uhc;
            #pragma unroll
            for (int g = 0; g < 4; ++g)
                xvB[g] = *reinterpret_cast<const f32x2*>(xr + g * HIDDEN);
        }

        for (int t = 1; t < T_STEPS; ++t) {
            GROUP_PHASE(0, xvA, cA0, cA1, t)
            GROUP_PHASE(1, xvB, cB0, cB1, t)
        }
#undef GROUP_PHASE
#undef GROUP_UPDATE
#undef STLDS
#undef CHK

        if (tid < 256) {
            f32x2 cvA = { cA0, cA1 };
            f32x2 cvB = { cB0, cB1 };
            *reinterpret_cast<f32x2*>(cfin + (size_t)(0 * 32 + ub) * HIDDEN + uhc) = cvA;
            *reinterpret_cast<f32x2*>(cfin + (size_t)(1 * 32 + ub) * HIDDEN + uhc) = cvB;
        }
    } else {
        // =================== DRAFTING GEMM ROLE ============================
        char* sA = (char*)smem;            // 128 rows x 64 bf16 = 16KB
        char* sB = (char*)smem + 16384;    // 80 rows x 64 bf16  = 10KB
        const int gbid = blockIdx.x - NBLK;     // 0..223
        const int w = tid >> 6, lane = tid & 63;
        const unsigned short* Abf = hsbf;

        for (int L = gbid; L < NTILE_M * NTILE_N; L += NGEMM) {
            int mi = L / NTILE_N, ni = L - mi * NTILE_N;
            int m0 = mi * 128, n0 = ni * 80;
            f32x4 acc[5] = {};

            for (int kc = 0; kc < 8; ++kc) {
                int k0 = kc * 64;
                // -------- A tile: sentinel-polled IC loads (2x16B/thread)
                int row0 = tid >> 3, slot = tid & 7;
                int row1 = row0 + 64;
                const char* a0p = (const char*)(Abf + (size_t)(m0 + row0) * HIDDEN + k0 + slot * 8);
                const char* a1p = (const char*)(Abf + (size_t)(m0 + row1) * HIDDEN + k0 + slot * 8);
                // canary: 1 dword per slot, block-wide vote, strong backoff
                for (int rnd = 0; rnd < (1 << 20); ++rnd) {
                    unsigned v0 = ld4ic(a0p), v1 = ld4ic(a1p);
                    asm volatile("s_waitcnt vmcnt(0)" : "+v"(v0), "+v"(v1));
                    int bad = (v0 == 0xFFFFFFFFu) || (v1 == 0xFFFFFFFFu);
                    if (__syncthreads_count(bad) == 0) break;
                    __builtin_amdgcn_s_sleep(16);
                }
                // full load + full check (usually one round)
                for (int rnd = 0; rnd < (1 << 16); ++rnd) {
                    i32x4 q0 = ld16ic(a0p), q1 = ld16ic(a1p);
                    asm volatile("s_waitcnt vmcnt(0)" : "+v"(q0), "+v"(q1));
                    unsigned mx = 0u;
                    #pragma unroll
                    for (int j = 0; j < 4; ++j) {
                        mx = (mx > (unsigned)q0[j]) ? mx : (unsigned)q0[j];
                        mx = (mx > (unsigned)q1[j]) ? mx : (unsigned)q1[j];
                    }
                    int bad = (mx == 0xFFFFFFFFu);
                    if (__syncthreads_count(bad) == 0) {
                        __builtin_amdgcn_sched_barrier(0);
                        *reinterpret_cast<i32x4*>(sA + row0 * 128 + ((slot ^ (row0 & 7)) * 16)) = q0;
                        *reinterpret_cast<i32x4*>(sA + row1 * 128 + ((slot ^ (row1 & 7)) * 16)) = q1;
                        break;
                    }
                    __builtin_amdgcn_s_sleep(4);
                }
                // -------- B tile: regular cached loads (640 x 16B slots)
                {
                    int s = tid;                       // 0..511
                    int br = s >> 3, bs = s & 7;
                    i32x4 v = *reinterpret_cast<const i32x4*>(Btbf + (size_t)(n0 + br) * HIDDEN + k0 + bs * 8);
                    *reinterpret_cast<i32x4*>(sB + br * 128 + ((bs ^ (br & 7)) * 16)) = v;
                    if (tid < 128) {
                        s = 512 + tid;
                        br = s >> 3; bs = s & 7;
                        v = *reinterpret_cast<const i32x4*>(Btbf + (size_t)(n0 + br) * HIDDEN + k0 + bs * 8);
                        *reinterpret_cast<i32x4*>(sB + br * 128 + ((bs ^ (br & 7)) * 16)) = v;
                    }
                }
                __syncthreads();
                // -------- MFMA: wave w owns rows [w*16, w*16+16)
                #pragma unroll
                for (int k2 = 0; k2 < 2; ++k2) {
                    int arow = w * 16 + (lane & 15);
                    int aoff = (k2 * 64 + (lane >> 4) * 16) ^ ((arow & 7) << 4);
                    bf16x8 a = *reinterpret_cast<const bf16x8*>(sA + arow * 128 + aoff);
                    #pragma unroll
                    for (int cf = 0; cf < 5; ++cf) {
                        int brow = cf * 16 + (lane & 15);
                        int boff = (k2 * 64 + (lane >> 4) * 16) ^ ((brow & 7) << 4);
                        bf16x8 b = *reinterpret_cast<const bf16x8*>(sB + brow * 128 + boff);
                        acc[cf] = __builtin_amdgcn_mfma_f32_16x16x32_bf16(a, b, acc[cf], 0, 0, 0);
                    }
                }
                __syncthreads();
            }
            // -------- epilogue
            #pragma unroll
            for (int cf = 0; cf < 5; ++cf) {
                int col = n0 + cf * 16 + (lane & 15);
                float bv = bias[col];
                #pragma unroll
                for (int r = 0; r < 4; ++r) {
                    int row = m0 + w * 16 + (lane >> 4) * 4 + r;
                    Cout[(size_t)row * VOCAB + col] = acc[cf][r] + bv;
                }
            }
        }
    }
}

// ---------------------------------------------------------------------------
__global__ void finalize_hc(const float* __restrict__ hfin, const float* __restrict__ cfin,
                            float* __restrict__ out) {
    int i = blockIdx.x * 256 + threadIdx.x;       // 0..65535
    size_t base = (size_t)M_ROWS * VOCAB;
    if (i < BATCH * HIDDEN)
        out[base + i] = hfin[i];
    else
        out[base + i] = cfin[i - BATCH * HIDDEN];
}

extern "C" void kernel_launch(void* const* d_in, const int* in_sizes, int n_in,
                              void* d_out, int out_size, void* d_ws, size_t ws_size,
                              hipStream_t stream) {
    (void)in_sizes; (void)n_in; (void)out_size; (void)ws_size;
    const int*   input_ = (const int*)  d_in[0];
    const float* Emb    = (const float*)d_in[1];
    const float* Wxi    = (const float*)d_in[2];
    const float* Whi    = (const float*)d_in[3];
    const float* bi     = (const float*)d_in[4];
    const float* Wxf    = (const float*)d_in[5];
    const float* Whf    = (const float*)d_in[6];
    const float* bf_    = (const float*)d_in[7];
    const float* Wxc    = (const float*)d_in[8];
    const float* Whc    = (const float*)d_in[9];
    const float* bc     = (const float*)d_in[10];
    const float* Wxo    = (const float*)d_in[11];
    const float* Who    = (const float*)d_in[12];
    const float* bo     = (const float*)d_in[13];
    const float* W      = (const float*)d_in[14];
    const float* b      = (const float*)d_in[15];
    float* out = (float*)d_out;

    char* ws = (char*)d_ws;
    float*          xg   = (float*)         (ws);                 // 67,108,864
    unsigned short* hsbf = (unsigned short*)(ws +  67108864);     //  8,388,608
    unsigned short* Wtbf = (unsigned short*)(ws +  75497472);     // 10,240,000
    unsigned short* WhT  = (unsigned short*)(ws +  85737472);     //  2,097,152
    float*          hfin = (float*)         (ws +  87834624);     //    131,072
    float*          cbuf = (float*)         (ws +  87965696);     //    131,072

    poison_hsbf<<<2048, 256, 0, stream>>>((unsigned*)hsbf);
    wt_convert<<<dim3(313, 16), dim3(32, 32), 0, stream>>>(W, Wtbf);
    wh_convert<<<dim3(16, 16, 4), dim3(32, 32), 0, stream>>>(Whi, Whf, Whc, Who, WhT);
    xproj<<<dim3(32, 64), 256, 0, stream>>>(input_, Emb, Wxi, Wxf, Wxc, Wxo,
                                            bi, bf_, bc, bo, xg);

    {
        const float* xg_c = xg;
        const unsigned short* WhT_c = WhT;
        unsigned short* hsbf_p = hsbf;
        float* hfin_p = hfin; float* cbuf_p = cbuf;
        const unsigned short* Wtbf_c = Wtbf;
        const float* b_c = b;
        float* out_p = out;
        void* args[] = { (void*)&xg_c, (void*)&WhT_c, (void*)&hsbf_p,
                         (void*)&hfin_p, (void*)&cbuf_p,
                         (void*)&Wtbf_c, (void*)&b_c, (void*)&out_p };
        hipLaunchCooperativeKernel((void*)lstm_fused, dim3(NLAUNCH), dim3(512), args, 0, stream);
    }

    finalize_hc<<<256, 256, 0, stream>>>(hfin, cbuf, out);
}